// Round 1
// baseline (1360.218 us; speedup 1.0000x reference)
//
#include <hip/hip_runtime.h>

static constexpr int Hd = 768;    // H
static constexpr int H2 = 1536;   // 2H
static constexpr int Cn = 64;     // C (labels)

// ---------------- scatter pooling ----------------
__global__ void k_init_widx(int* widx, int Wd) {
    int i = blockIdx.x * 256 + threadIdx.x;
    if (i < Wd) widx[i] = -1;
}

__global__ void k_scatter(const int* __restrict__ wmask, int* widx, int L, int Wd) {
    int i = blockIdx.x * 256 + threadIdx.x;
    if (i < L) {
        int m = wmask[i];
        if (m > 0 && m <= Wd) atomicMax(&widx[m - 1], i);  // last token wins
    }
}

__global__ void k_build_we(const float4* __restrict__ tok, const int* __restrict__ widx,
                           float4* __restrict__ we, int Wd) {
    int i = blockIdx.x * 256 + threadIdx.x;   // over Wd * Hd/4
    const int cols = Hd / 4;
    int w = i / cols, c = i - w * cols;
    if (w >= Wd) return;
    int idx = widx[w];
    we[i] = (idx >= 0) ? tok[idx * cols + c] : float4{0.f, 0.f, 0.f, 0.f};
}

// ---------------- generic f32 tiled GEMM: C = A*B (+bias) ----------------
// 64x64 tile, BK=16, 256 threads, 4x4 microtile.
__global__ __launch_bounds__(256)
void k_gemm(const float* __restrict__ A, int lda,
            const float* __restrict__ B, int ldb,
            const float* __restrict__ bias,
            float* __restrict__ C, int ldc, int K) {
    __shared__ float As[16][68];
    __shared__ float Bs[16][68];
    const int tid = threadIdx.x;
    const int tx = tid & 15, ty = tid >> 4;
    const int m0 = blockIdx.y * 64, n0 = blockIdx.x * 64;
    float acc[4][4] = {};
    for (int k0 = 0; k0 < K; k0 += 16) {
#pragma unroll
        for (int e = 0; e < 4; ++e) {
            int ii = tid + 256 * e;
            int kk = ii & 15, m = ii >> 4;           // coalesced along k within a row
            As[kk][m] = A[(m0 + m) * (long)lda + k0 + kk];
            int kk2 = ii >> 6, jj = ii & 63;         // coalesced along n
            Bs[kk2][jj] = B[(k0 + kk2) * (long)ldb + n0 + jj];
        }
        __syncthreads();
#pragma unroll
        for (int k = 0; k < 16; ++k) {
            float4 a4 = *(const float4*)&As[k][ty * 4];
            float4 b4 = *(const float4*)&Bs[k][tx * 4];
            float av[4] = {a4.x, a4.y, a4.z, a4.w};
            float bv[4] = {b4.x, b4.y, b4.z, b4.w};
#pragma unroll
            for (int i = 0; i < 4; ++i)
#pragma unroll
                for (int j = 0; j < 4; ++j) acc[i][j] += av[i] * bv[j];
        }
        __syncthreads();
    }
#pragma unroll
    for (int i = 0; i < 4; ++i) {
        int m = m0 + ty * 4 + i;
#pragma unroll
        for (int j = 0; j < 4; ++j) {
            int n = n0 + tx * 4 + j;
            float v = acc[i][j];
            if (bias) v += bias[n];
            C[m * (long)ldc + n] = v;
        }
    }
}

// ---------------- fused main kernel ----------------
// One block per word w. Rows = 64 labels (c), cols = j in 12 tiles of 64.
// P[w,c,j] = sum_k t1[w,k]*lb1[c,k]*W1c[k,j]; h = relu(A[w,j]+B[c,j]+P);
// scores[w,c,r] = sum_j h*W2[j,r] + b2[r], reduced in registers (no atomics).
__global__ __launch_bounds__(256)
void k_main(const float* __restrict__ t,    // (Wd, 1536)
            const float* __restrict__ lb,   // (64, 1536)
            const float* __restrict__ W1,   // (2304, 768)
            const float* __restrict__ Aw,   // (Wd, 768)
            const float* __restrict__ Bc,   // (64, 768) includes b1
            const float* __restrict__ W2,   // (768, 3)
            const float* __restrict__ b2,   // (3,)
            float* __restrict__ out,        // (Wd, 64, 3)
            int Wd) {
    __shared__ float Xs[16][68];
    __shared__ float Ws[16][68];
    __shared__ float W2s[Hd * 3];
    const int tid = threadIdx.x;
    const int tx = tid & 15, ty = tid >> 4;
    const int w = blockIdx.x;

    for (int i = tid; i < Hd * 3; i += 256) W2s[i] = W2[i];  // visible after first barrier

    const float* t1 = t + (long)w * H2 + Hd;
    const float* W1c = W1 + (long)2 * Hd * Hd;  // rows 2H..3H-1
    float sacc[4][3] = {};

    for (int j0 = 0; j0 < Hd; j0 += 64) {
        float p[4][4] = {};
        for (int k0 = 0; k0 < Hd; k0 += 16) {
#pragma unroll
            for (int e = 0; e < 4; ++e) {
                int ii = tid + 256 * e;
                int kk = ii & 15, c = ii >> 4;
                Xs[kk][c] = lb[c * (long)H2 + Hd + k0 + kk] * t1[k0 + kk];
                int kk2 = ii >> 6, jj = ii & 63;
                Ws[kk2][jj] = W1c[(k0 + kk2) * (long)Hd + j0 + jj];
            }
            __syncthreads();
#pragma unroll
            for (int k = 0; k < 16; ++k) {
                float4 a4 = *(const float4*)&Xs[k][ty * 4];
                float4 b4 = *(const float4*)&Ws[k][tx * 4];
                float av[4] = {a4.x, a4.y, a4.z, a4.w};
                float bv[4] = {b4.x, b4.y, b4.z, b4.w};
#pragma unroll
                for (int i = 0; i < 4; ++i)
#pragma unroll
                    for (int j = 0; j < 4; ++j) p[i][j] += av[i] * bv[j];
            }
            __syncthreads();
        }
        // epilogue for this j-tile
        float4 av4 = *(const float4*)&Aw[(long)w * Hd + j0 + tx * 4];
        float aj[4] = {av4.x, av4.y, av4.z, av4.w};
#pragma unroll
        for (int i = 0; i < 4; ++i) {
            int c = ty * 4 + i;
            float4 bv4 = *(const float4*)&Bc[c * (long)Hd + j0 + tx * 4];
            float bj[4] = {bv4.x, bv4.y, bv4.z, bv4.w};
#pragma unroll
            for (int jj = 0; jj < 4; ++jj) {
                float h = p[i][jj] + aj[jj] + bj[jj];
                h = h > 0.f ? h : 0.f;
                int j = j0 + tx * 4 + jj;
#pragma unroll
                for (int r = 0; r < 3; ++r) sacc[i][r] += h * W2s[j * 3 + r];
            }
        }
    }
    // reduce across the 16 tx-lanes (within-wave groups of 16)
#pragma unroll
    for (int i = 0; i < 4; ++i)
#pragma unroll
        for (int r = 0; r < 3; ++r) {
            float v = sacc[i][r];
            v += __shfl_xor(v, 1);
            v += __shfl_xor(v, 2);
            v += __shfl_xor(v, 4);
            v += __shfl_xor(v, 8);
            sacc[i][r] = v;
        }
    if (tx == 0) {
#pragma unroll
        for (int i = 0; i < 4; ++i) {
            int c = ty * 4 + i;
#pragma unroll
            for (int r = 0; r < 3; ++r)
                out[((long)w * Cn + c) * 3 + r] = sacc[i][r] + b2[r];
        }
    }
}

extern "C" void kernel_launch(void* const* d_in, const int* in_sizes, int n_in,
                              void* d_out, int out_size, void* d_ws, size_t ws_size,
                              hipStream_t stream) {
    const float* tok    = (const float*)d_in[0];
    const int*   wmask  = (const int*)d_in[1];
    const float* labe   = (const float*)d_in[3];
    const float* W_tok  = (const float*)d_in[4];
    const float* b_tok  = (const float*)d_in[5];
    const float* W_lab  = (const float*)d_in[6];
    const float* b_lab  = (const float*)d_in[7];
    const float* W1     = (const float*)d_in[8];
    const float* b1     = (const float*)d_in[9];
    const float* W2     = (const float*)d_in[10];
    const float* b2     = (const float*)d_in[11];
    float* out = (float*)d_out;

    const int L  = in_sizes[1];
    const int Wd = out_size / (Cn * 3);   // 1024

    // workspace layout
    char* ws = (char*)d_ws;
    int*   widx = (int*)ws;                                   size_t off = 4096;
    float* we   = (float*)(ws + off);  off += (size_t)Wd * Hd * 4;
    float* tbuf = (float*)(ws + off);  off += (size_t)Wd * H2 * 4;
    float* lbuf = (float*)(ws + off);  off += (size_t)Cn * H2 * 4;
    float* Abuf = (float*)(ws + off);  off += (size_t)Wd * Hd * 4;
    float* Bbuf = (float*)(ws + off);  off += (size_t)Cn * Hd * 4;

    // 1) scatter pooling -> we
    k_init_widx<<<(Wd + 255) / 256, 256, 0, stream>>>(widx, Wd);
    k_scatter<<<(L + 255) / 256, 256, 0, stream>>>(wmask, widx, L, Wd);
    k_build_we<<<(Wd * (Hd / 4) + 255) / 256, 256, 0, stream>>>((const float4*)tok, widx, (float4*)we, Wd);

    // 2) t = we @ W_tok + b_tok     (Wd x 1536)
    k_gemm<<<dim3(H2 / 64, Wd / 64), 256, 0, stream>>>(we, Hd, W_tok, H2, b_tok, tbuf, H2, Hd);
    // 3) lb = label_embs @ W_lab + b_lab   (64 x 1536)
    k_gemm<<<dim3(H2 / 64, 1), 256, 0, stream>>>(labe, Hd, W_lab, H2, b_lab, lbuf, H2, Hd);
    // 4) A = t0 @ W1a              (Wd x 768)
    k_gemm<<<dim3(Hd / 64, Wd / 64), 256, 0, stream>>>(tbuf, H2, W1, Hd, nullptr, Abuf, Hd, Hd);
    // 5) B = lb0 @ W1b + b1        (64 x 768)
    k_gemm<<<dim3(Hd / 64, 1), 256, 0, stream>>>(lbuf, H2, W1 + (size_t)Hd * Hd, Hd, b1, Bbuf, Hd, Hd);

    // 6) fused P-GEMM + relu + W2 contraction
    k_main<<<dim3(Wd), 256, 0, stream>>>(tbuf, lbuf, W1, Abuf, Bbuf, W2, b2, out, Wd);
}

// Round 2
// 619.153 us; speedup vs baseline: 2.1969x; 2.1969x over previous
//
#include <hip/hip_runtime.h>
#include <hip/hip_bf16.h>

static constexpr int Hd = 768;    // H
static constexpr int H2 = 1536;   // 2H
static constexpr int Cn = 64;     // C (labels)

typedef __attribute__((ext_vector_type(8))) short short8;
typedef __attribute__((ext_vector_type(4))) float f32x4;

__device__ inline unsigned int f2bf2(float a, float b) {
    __hip_bfloat162 h = __float22bfloat162_rn(float2{a, b});
    return *reinterpret_cast<unsigned int*>(&h);
}

__device__ inline void gload16(const void* g, void* l) {
    __builtin_amdgcn_global_load_lds(
        (const __attribute__((address_space(1))) unsigned int*)g,
        (__attribute__((address_space(3))) unsigned int*)l, 16, 0, 0);
}

// ---------------- scatter pooling ----------------
__global__ void k_init_widx(int* widx, int Wd) {
    int i = blockIdx.x * 256 + threadIdx.x;
    if (i < Wd) widx[i] = -1;
}

__global__ void k_scatter(const int* __restrict__ wmask, int* widx, int L, int Wd) {
    int i = blockIdx.x * 256 + threadIdx.x;
    if (i < L) {
        int m = wmask[i];
        if (m > 0 && m <= Wd) atomicMax(&widx[m - 1], i);  // last token wins
    }
}

__global__ void k_build_we(const float4* __restrict__ tok, const int* __restrict__ widx,
                           float4* __restrict__ we, int Wd) {
    int i = blockIdx.x * 256 + threadIdx.x;
    const int cols = Hd / 4;
    int w = i / cols, c = i - w * cols;
    if (w >= Wd) return;
    int idx = widx[w];
    we[i] = (idx >= 0) ? tok[idx * cols + c] : float4{0.f, 0.f, 0.f, 0.f};
}

// ---------------- generic f32 tiled GEMM (prelims) ----------------
__global__ __launch_bounds__(256)
void k_gemm(const float* __restrict__ A, int lda,
            const float* __restrict__ B, int ldb,
            const float* __restrict__ bias,
            float* __restrict__ C, int ldc, int K) {
    __shared__ float As[16][68];
    __shared__ float Bs[16][68];
    const int tid = threadIdx.x;
    const int tx = tid & 15, ty = tid >> 4;
    const int m0 = blockIdx.y * 64, n0 = blockIdx.x * 64;
    float acc[4][4] = {};
    for (int k0 = 0; k0 < K; k0 += 16) {
#pragma unroll
        for (int e = 0; e < 4; ++e) {
            int ii = tid + 256 * e;
            int kk = ii & 15, m = ii >> 4;
            As[kk][m] = A[(m0 + m) * (long)lda + k0 + kk];
            int kk2 = ii >> 6, jj = ii & 63;
            Bs[kk2][jj] = B[(k0 + kk2) * (long)ldb + n0 + jj];
        }
        __syncthreads();
#pragma unroll
        for (int k = 0; k < 16; ++k) {
            float4 a4 = *(const float4*)&As[k][ty * 4];
            float4 b4 = *(const float4*)&Bs[k][tx * 4];
            float av[4] = {a4.x, a4.y, a4.z, a4.w};
            float bv[4] = {b4.x, b4.y, b4.z, b4.w};
#pragma unroll
            for (int i = 0; i < 4; ++i)
#pragma unroll
                for (int j = 0; j < 4; ++j) acc[i][j] += av[i] * bv[j];
        }
        __syncthreads();
    }
#pragma unroll
    for (int i = 0; i < 4; ++i) {
        int m = m0 + ty * 4 + i;
#pragma unroll
        for (int j = 0; j < 4; ++j) {
            int n = n0 + tx * 4 + j;
            float v = acc[i][j];
            if (bias) v += bias[n];
            C[m * (long)ldc + n] = v;
        }
    }
}

// ---------------- W1c transpose + bf16 convert: W1ct[j][k] = bf16(W1[2H+k][j]) ----
__global__ __launch_bounds__(256)
void k_w1ct(const float* __restrict__ W1, unsigned short* __restrict__ W1ct) {
    __shared__ float tile[64][65];
    const int j0 = blockIdx.x * 64, k0 = blockIdx.y * 64;
    for (int idx = threadIdx.x; idx < 4096; idx += 256) {
        int kk = idx >> 6, jj = idx & 63;
        tile[kk][jj] = W1[(size_t)(2 * Hd + k0 + kk) * Hd + j0 + jj];
    }
    __syncthreads();
    for (int idx = threadIdx.x; idx < 4096; idx += 256) {
        int jj = idx >> 6, kk = idx & 63;
        __hip_bfloat16 h = __float2bfloat16(tile[kk][jj]);
        W1ct[(size_t)(j0 + jj) * Hd + k0 + kk] = *reinterpret_cast<unsigned short*>(&h);
    }
}

// ---------------- MFMA main kernel ----------------
// Block: 128 rows ((w0,c0..63),(w1,c0..63)) x j in 6 chunks of 128.
// P = X @ W1c with X[(w,c),k] = t1[w,k]*lb1[c,k] built on the fly (bf16).
// Epilogue per chunk: h = relu(P + Aw[w,j] + Bc[c,j]); sacc[row][r] += h*W2[j][r].
__global__ __launch_bounds__(256)
void k_mfma(const float* __restrict__ t,             // (Wd,1536) f32
            const float* __restrict__ lb,            // (64,1536) f32
            const unsigned short* __restrict__ W1ct, // (768,768) bf16 [j][k]
            const float* __restrict__ Aw,            // (Wd,768) f32
            const float* __restrict__ Bc,            // (64,768) f32 (includes b1)
            const float* __restrict__ W2,            // (768,3)
            const float* __restrict__ b2,            // (3,)
            float* __restrict__ out) {               // (Wd,64,3)
    __shared__ unsigned short Xs[128 * 40];   // padded stride 40 (80 B)
    __shared__ unsigned short Ws[128 * 32];   // unpadded (global_load_lds)
    __shared__ float W2s[Hd * 3];
    __shared__ float sred[128 * 3];

    const int tid = threadIdx.x;
    const int wave = tid >> 6, lane = tid & 63;
    const int quad = lane >> 4, l15 = lane & 15;
    const int mhalf = wave >> 1, nhalf = wave & 1;
    const int wb = blockIdx.x;                    // row base = wb*128

    for (int i = tid; i < Hd * 3; i += 256) W2s[i] = W2[i];
    for (int i = tid; i < 128 * 3; i += 256) sred[i] = 0.f;

    // Xs staging map: thread -> row (0..127), k-seg (0 or 16)
    const int xr = tid >> 1;
    const int xks = (tid & 1) * 16;
    const float* t1row = t + (size_t)(wb * 2 + (xr >> 6)) * H2 + Hd;
    const float* lbrow = lb + (size_t)(xr & 63) * H2 + Hd;

    // Ws staging map: wave covers rows wave*32..+31 in 2 chunks of 16
    const int wr0 = wave * 32 + (lane >> 2);
    const int wkb = (lane & 3) * 8;

    float sacc[4][4][3];
#pragma unroll
    for (int a = 0; a < 4; ++a)
#pragma unroll
        for (int b = 0; b < 4; ++b)
#pragma unroll
            for (int r = 0; r < 3; ++r) sacc[a][b][r] = 0.f;

    const int w_wave = wb * 2 + mhalf;

    for (int chunk = 0; chunk < 6; ++chunk) {
        const int j0 = chunk * 128;
        f32x4 acc[4][4];
#pragma unroll
        for (int mt = 0; mt < 4; ++mt)
#pragma unroll
            for (int nt = 0; nt < 4; ++nt) acc[mt][nt] = (f32x4){0.f, 0.f, 0.f, 0.f};

        for (int k0 = 0; k0 < Hd; k0 += 32) {
            __syncthreads();   // previous iter's fragment reads done
            // ---- Xs: compute 16 products, pack bf16, 2x ds_write_b128 ----
            {
                const float* tp = t1row + k0 + xks;
                const float* lp = lbrow + k0 + xks;
                float4 ta = *(const float4*)(tp + 0), tb = *(const float4*)(tp + 4);
                float4 tc = *(const float4*)(tp + 8), td = *(const float4*)(tp + 12);
                float4 la = *(const float4*)(lp + 0), lbv = *(const float4*)(lp + 4);
                float4 lc = *(const float4*)(lp + 8), ld = *(const float4*)(lp + 12);
                union { unsigned int u[4]; short8 s; } o0, o1;
                o0.u[0] = f2bf2(ta.x * la.x, ta.y * la.y);
                o0.u[1] = f2bf2(ta.z * la.z, ta.w * la.w);
                o0.u[2] = f2bf2(tb.x * lbv.x, tb.y * lbv.y);
                o0.u[3] = f2bf2(tb.z * lbv.z, tb.w * lbv.w);
                o1.u[0] = f2bf2(tc.x * lc.x, tc.y * lc.y);
                o1.u[1] = f2bf2(tc.z * lc.z, tc.w * lc.w);
                o1.u[2] = f2bf2(td.x * ld.x, td.y * ld.y);
                o1.u[3] = f2bf2(td.z * ld.z, td.w * ld.w);
                *(short8*)&Xs[xr * 40 + xks + 0] = o0.s;
                *(short8*)&Xs[xr * 40 + xks + 8] = o1.s;
            }
            // ---- Ws: direct-to-LDS, 2 chunks of 16 rows per wave ----
            {
                const unsigned short* g0 = W1ct + (size_t)(j0 + wr0) * Hd + k0 + wkb;
                gload16(g0, &Ws[(wave * 32) * 32]);
                gload16(g0 + 16 * Hd, &Ws[(wave * 32 + 16) * 32]);
            }
            __syncthreads();
            // ---- fragments + MFMA ----
            short8 af[4], bfr[4];
#pragma unroll
            for (int mt = 0; mt < 4; ++mt)
                af[mt] = *(const short8*)&Xs[(mhalf * 64 + mt * 16 + l15) * 40 + quad * 8];
#pragma unroll
            for (int nt = 0; nt < 4; ++nt)
                bfr[nt] = *(const short8*)&Ws[(nhalf * 64 + nt * 16 + l15) * 32 + quad * 8];
#pragma unroll
            for (int mt = 0; mt < 4; ++mt)
#pragma unroll
                for (int nt = 0; nt < 4; ++nt)
                    acc[mt][nt] = __builtin_amdgcn_mfma_f32_16x16x32_bf16(
                        af[mt], bfr[nt], acc[mt][nt], 0, 0, 0);
        }

        // ---- epilogue: h = relu(P + Aw + Bc), sacc += h * W2 ----
#pragma unroll
        for (int nt = 0; nt < 4; ++nt) {
            const int jn = j0 + nhalf * 64 + nt * 16 + l15;
            const float aw = Aw[(size_t)w_wave * Hd + jn];
            const float w20 = W2s[jn * 3 + 0], w21 = W2s[jn * 3 + 1], w22 = W2s[jn * 3 + 2];
#pragma unroll
            for (int mt = 0; mt < 4; ++mt)
#pragma unroll
                for (int reg = 0; reg < 4; ++reg) {
                    const int c = mt * 16 + quad * 4 + reg;
                    float h = acc[mt][nt][reg] + aw + Bc[(size_t)c * Hd + jn];
                    h = h > 0.f ? h : 0.f;
                    sacc[mt][reg][0] += h * w20;
                    sacc[mt][reg][1] += h * w21;
                    sacc[mt][reg][2] += h * w22;
                }
        }
    }

    // ---- cross-lane reduce (over the 16 j-lanes), combine nhalf waves via LDS ----
#pragma unroll
    for (int mt = 0; mt < 4; ++mt)
#pragma unroll
        for (int reg = 0; reg < 4; ++reg)
#pragma unroll
            for (int r = 0; r < 3; ++r) {
                float v = sacc[mt][reg][r];
                v += __shfl_xor(v, 1);
                v += __shfl_xor(v, 2);
                v += __shfl_xor(v, 4);
                v += __shfl_xor(v, 8);
                if (l15 == 0)
                    atomicAdd(&sred[(mhalf * 64 + mt * 16 + quad * 4 + reg) * 3 + r], v);
            }
    __syncthreads();
    const float b20 = b2[0], b21 = b2[1], b22 = b2[2];
    for (int i = tid; i < 128 * 3; i += 256) {
        int r = i - (i / 3) * 3;
        float bb = (r == 0) ? b20 : ((r == 1) ? b21 : b22);
        out[(size_t)wb * 384 + i] = sred[i] + bb;
    }
}

extern "C" void kernel_launch(void* const* d_in, const int* in_sizes, int n_in,
                              void* d_out, int out_size, void* d_ws, size_t ws_size,
                              hipStream_t stream) {
    const float* tok    = (const float*)d_in[0];
    const int*   wmask  = (const int*)d_in[1];
    const float* labe   = (const float*)d_in[3];
    const float* W_tok  = (const float*)d_in[4];
    const float* b_tok  = (const float*)d_in[5];
    const float* W_lab  = (const float*)d_in[6];
    const float* b_lab  = (const float*)d_in[7];
    const float* W1     = (const float*)d_in[8];
    const float* b1     = (const float*)d_in[9];
    const float* W2     = (const float*)d_in[10];
    const float* b2     = (const float*)d_in[11];
    float* out = (float*)d_out;

    const int L  = in_sizes[1];
    const int Wd = out_size / (Cn * 3);   // 1024

    char* ws = (char*)d_ws;
    int*   widx = (int*)ws;                                    size_t off = 4096;
    float* we   = (float*)(ws + off);  off += (size_t)Wd * Hd * 4;
    float* tbuf = (float*)(ws + off);  off += (size_t)Wd * H2 * 4;
    float* lbuf = (float*)(ws + off);  off += (size_t)Cn * H2 * 4;
    float* Abuf = (float*)(ws + off);  off += (size_t)Wd * Hd * 4;
    float* Bbuf = (float*)(ws + off);  off += (size_t)Cn * Hd * 4;
    unsigned short* W1ct = (unsigned short*)(ws + off); off += (size_t)Hd * Hd * 2;

    // 1) scatter pooling
    k_init_widx<<<(Wd + 255) / 256, 256, 0, stream>>>(widx, Wd);
    k_scatter<<<(L + 255) / 256, 256, 0, stream>>>(wmask, widx, L, Wd);
    k_build_we<<<(Wd * (Hd / 4) + 255) / 256, 256, 0, stream>>>((const float4*)tok, widx, (float4*)we, Wd);

    // 2) W1c -> bf16 transposed [j][k]
    k_w1ct<<<dim3(Hd / 64, Hd / 64), 256, 0, stream>>>(W1, W1ct);

    // 3) prelim GEMMs (f32)
    k_gemm<<<dim3(H2 / 64, Wd / 64), 256, 0, stream>>>(we, Hd, W_tok, H2, b_tok, tbuf, H2, Hd);
    k_gemm<<<dim3(H2 / 64, 1),       256, 0, stream>>>(labe, Hd, W_lab, H2, b_lab, lbuf, H2, Hd);
    k_gemm<<<dim3(Hd / 64, Wd / 64), 256, 0, stream>>>(tbuf, H2, W1, Hd, nullptr, Abuf, Hd, Hd);
    k_gemm<<<dim3(Hd / 64, 1),       256, 0, stream>>>(lbuf, H2, W1 + (size_t)Hd * Hd, Hd, b1, Bbuf, Hd, Hd);

    // 4) MFMA P-GEMM + fused epilogue
    k_mfma<<<dim3(Wd / 2), 256, 0, stream>>>(tbuf, lbuf, W1ct, Abuf, Bbuf, W2, b2, out);
}